// Round 19
// baseline (1077.629 us; speedup 1.0000x reference)
//
#include <hip/hip_runtime.h>
#include <hip/hip_bf16.h>

#define GG 128
#define G2 (GG*GG)
#define CC 256
#define HH 4
#define NPTS 100000
#define NB 2
#define LN_EPS 1e-5f
#define CHUNK 256
#define NTILE 3125
#define PBLK 512

typedef __attribute__((ext_vector_type(8))) short short8v;
typedef __attribute__((ext_vector_type(4))) float float4v;

__device__ __forceinline__ unsigned short bfround(float x){
    unsigned u = __float_as_uint(x);
    return (unsigned short)((u + 0x7FFFu + ((u >> 16) & 1u)) >> 16);
}
__device__ __forceinline__ float bfval(unsigned short h){
    return __uint_as_float(((unsigned)h) << 16);
}

__global__ __launch_bounds__(256) void prep_b2_kernel(
    const float* __restrict__ Wk, const float* __restrict__ Wv,
    const float* __restrict__ kb, const float* __restrict__ vb,
    unsigned short* __restrict__ B2, float* __restrict__ bias_comb)
{
    int n = blockIdx.x;
    int t = threadIdx.x;
    const float* src = (n < 256) ? (Wk + (size_t)n*CC) : (Wv + (size_t)(n-256)*CC);
    float w = src[t];
    unsigned short h = bfround(w);
    unsigned short l = bfround(w - bfval(h));
    unsigned short* row = B2 + (size_t)n*768;
    row[t] = h;
    row[256 + t] = l;
    row[512 + t] = h;
    if (t == 0) bias_comb[n] = (n < 256) ? kb[n] : vb[n-256];
}

__global__ __launch_bounds__(256) void transpose_q_kernel(
    const float* __restrict__ qxy, const float* __restrict__ qxz,
    const float* __restrict__ qyz, float* __restrict__ qT)
{
    int blk = blockIdx.x;
    int plane = blk >> 10;
    int rem = blk & 1023;
    int cell0 = (rem >> 2) << 6;
    int c0 = (rem & 3) << 6;
    const float* q = plane == 0 ? qxy : (plane == 1 ? qxz : qyz);
    __shared__ float tile[64][65];
    int tx = threadIdx.x & 63;
    int ty = threadIdx.x >> 6;
    #pragma unroll
    for (int i = ty; i < 64; i += 4)
        tile[i][tx] = q[(size_t)(c0 + i)*G2 + cell0 + tx];
    __syncthreads();
    #pragma unroll
    for (int i = ty; i < 64; i += 4)
        qT[((size_t)plane*G2 + cell0 + i)*CC + c0 + tx] = tile[tx][i];
}

// ===== R19: PERSISTENT fused M=64 kernel — grid-stride tiles, feats prefetch =====
__global__ __launch_bounds__(512, 4) void point64_kernel(
    const float* __restrict__ feats, const float* __restrict__ bounds,
    const unsigned short* __restrict__ B2, const float* __restrict__ bias_comb,
    const float* __restrict__ lng, const float* __restrict__ lnb,
    const float* __restrict__ qT,
    unsigned short* __restrict__ Vout, float* __restrict__ s_out,
    int* __restrict__ cells, int* __restrict__ cnt)
{
    // phase A: Ahi[64][264] @0, Alo @33792 ; phase B: K_f32[64][260] @0 (alias)
    // coords[64*3] @67584, live across phases
    __shared__ __align__(16) char lraw[68352];
    unsigned short* Ahi = (unsigned short*)lraw;
    unsigned short* Alo = (unsigned short*)(lraw + 33792);
    float* K_f = (float*)lraw;
    float* coords_lds = (float*)(lraw + 67584);

    int t = threadIdx.x;
    int lane = t & 63;
    int w = t >> 6;                    // 0..7

    float lg0 = lng[lane], lg1 = lng[lane+64], lg2 = lng[lane+128], lg3 = lng[lane+192];
    float lb0 = lnb[lane], lb1 = lnb[lane+64], lb2 = lnb[lane+128], lb3 = lnb[lane+192];

    // preload first tile's feats
    float xr[8][4];
    {
        long long g0 = (long long)blockIdx.x * 64;
        #pragma unroll
        for (int r = 0; r < 8; r++){
            const float* f = feats + (size_t)(g0 + w*8 + r)*CC;
            xr[r][0] = f[lane];
            xr[r][1] = f[lane + 64];
            xr[r][2] = f[lane + 128];
            xr[r][3] = f[lane + 192];
        }
    }

    for (int tile = blockIdx.x; tile < NTILE; tile += gridDim.x){
        long long g0 = (long long)tile * 64;

        // ---- stage 1: coords + LN + bf16 hi/lo pack (uses prefetched xr) ----
        #pragma unroll
        for (int r = 0; r < 8; r++){
            int p = w*8 + r;
            float x0 = xr[r][0], x1 = xr[r][1], x2 = xr[r][2], x3 = xr[r][3];
            if (lane < 3){
                float l0 = bounds[2*lane], h0 = bounds[2*lane+1];
                float tnum = __fmul_rn(2.0f, __fsub_rn(x0, l0));
                float cv = __fsub_rn(__fdiv_rn(tnum, __fsub_rn(h0, l0)), 1.0f);
                x0 = cv;
                coords_lds[p*3 + lane] = cv;
            }
            float s1 = x0 + x1 + x2 + x3;
            float s2 = x0*x0 + x1*x1 + x2*x2 + x3*x3;
            #pragma unroll
            for (int off = 32; off; off >>= 1){
                s1 += __shfl_xor(s1, off);
                s2 += __shfl_xor(s2, off);
            }
            float mu = s1 * (1.0f/CC);
            float var = s2 * (1.0f/CC) - mu*mu;
            float rs = rsqrtf(var + LN_EPS);

            float f0 = (x0 - mu)*rs*lg0 + lb0;
            float f1 = (x1 - mu)*rs*lg1 + lb1;
            float f2 = (x2 - mu)*rs*lg2 + lb2;
            float f3 = (x3 - mu)*rs*lg3 + lb3;
            unsigned short h0 = bfround(f0), h1 = bfround(f1);
            unsigned short h2 = bfround(f2), h3 = bfround(f3);
            Ahi[p*264 + lane      ] = h0;  Alo[p*264 + lane      ] = bfround(f0 - bfval(h0));
            Ahi[p*264 + lane +  64] = h1;  Alo[p*264 + lane +  64] = bfround(f1 - bfval(h1));
            Ahi[p*264 + lane + 128] = h2;  Alo[p*264 + lane + 128] = bfround(f2 - bfval(h2));
            Ahi[p*264 + lane + 192] = h3;  Alo[p*264 + lane + 192] = bfround(f3 - bfval(h3));
        }
        __syncthreads();

        // ---- cells + cnt (hidden under GEMM) ----
        if (lane < 24){
            int r = lane / 3;
            int pl = lane - 3*r;
            int p = w*8 + r;
            long long gpt = g0 + p;
            int bb = (int)(gpt / NPTS);
            int ptp = (int)(gpt - (long long)bb*NPTS);
            float cx = coords_lds[p*3], cy = coords_lds[p*3+1], cz = coords_lds[p*3+2];
            float a = (pl == 2) ? cy : cx;
            float b2 = (pl == 0) ? cy : cz;
            float ua = __fmul_rn(__fadd_rn(__fmul_rn(a, 0.5f), 0.5f), (float)(GG-1));
            float ub = __fmul_rn(__fadd_rn(__fmul_rn(b2,0.5f), 0.5f), (float)(GG-1));
            int gx = (int)ua; gx = gx < 0 ? 0 : (gx > GG-1 ? GG-1 : gx);
            int gy = (int)ub; gy = gy < 0 ? 0 : (gy > GG-1 ? GG-1 : gy);
            int cell = gx*GG + gy;
            int bp = bb*3 + pl;
            cells[(size_t)bp*NPTS + ptp] = cell;
            atomicAdd(&cnt[(size_t)bp*G2 + cell], 1);
        }

        // ---- stage 2: MFMA GEMM, wave-tile M=64 x N=64, K=768 ----
        {
            int apt = lane & 15;
            int krow = (lane >> 4) * 8;
            int n0 = w * 64;
            int bcol = n0 + (lane & 15);
            float4v acc[4][4];
            #pragma unroll
            for (int ni = 0; ni < 4; ni++){
                float bz = bias_comb[n0 + ni*16 + (lane & 15)];
                #pragma unroll
                for (int mi = 0; mi < 4; mi++){
                    acc[mi][ni][0]=bz; acc[mi][ni][1]=bz;
                    acc[mi][ni][2]=bz; acc[mi][ni][3]=bz;
                }
            }
            #pragma unroll 2
            for (int ks = 0; ks < 24; ks++){
                int term = ks >> 3;
                int kk = (ks & 7)*32 + krow;
                int kglob = term*256 + kk;
                const unsigned short* Abase = (term < 2) ? Ahi : Alo;
                short8v a[4];
                #pragma unroll
                for (int mi = 0; mi < 4; mi++)
                    a[mi] = *reinterpret_cast<const short8v*>(Abase + (mi*16 + apt)*264 + kk);
                short8v bf[4];
                #pragma unroll
                for (int ni = 0; ni < 4; ni++)
                    bf[ni] = *reinterpret_cast<const short8v*>(
                        B2 + (size_t)(bcol + ni*16)*768 + kglob);
                #pragma unroll
                for (int mi = 0; mi < 4; mi++)
                    #pragma unroll
                    for (int ni = 0; ni < 4; ni++)
                        acc[mi][ni] = __builtin_amdgcn_mfma_f32_16x16x32_bf16(
                            a[mi], bf[ni], acc[mi][ni], 0, 0, 0);
            }
            __syncthreads();   // A reads done; K_f may alias A
            if (w < 4){
                #pragma unroll
                for (int ni = 0; ni < 4; ni++){
                    int ch = n0 + ni*16 + (lane & 15);
                    #pragma unroll
                    for (int mi = 0; mi < 4; mi++)
                        #pragma unroll
                        for (int r4 = 0; r4 < 4; r4++){
                            int pt = mi*16 + (lane >> 4)*4 + r4;
                            K_f[pt*260 + ch] = acc[mi][ni][r4];
                        }
                }
            } else {
                #pragma unroll
                for (int ni = 0; ni < 4; ni++){
                    int ch = (n0 - 256) + ni*16 + (lane & 15);
                    #pragma unroll
                    for (int mi = 0; mi < 4; mi++)
                        #pragma unroll
                        for (int r4 = 0; r4 < 4; r4++){
                            int pt = mi*16 + (lane >> 4)*4 + r4;
                            Vout[(size_t)(g0 + pt)*CC + ch] = bfround(acc[mi][ni][r4]);
                        }
                }
            }
        }
        __syncthreads();       // K_f visible

        // ---- prefetch next tile's feats (hides HBM latency under stage 3) ----
        {
            int ntile = tile + gridDim.x;
            if (ntile < NTILE){
                long long g0n = (long long)ntile * 64;
                #pragma unroll
                for (int r = 0; r < 8; r++){
                    const float* f = feats + (size_t)(g0n + w*8 + r)*CC;
                    xr[r][0] = f[lane];
                    xr[r][1] = f[lane + 64];
                    xr[r][2] = f[lane + 128];
                    xr[r][3] = f[lane + 192];
                }
            }
        }

        // ---- stage 3: lane-parallel s (8 waves x 8 points) ----
        {
            int grp = lane >> 3;
            int g   = lane & 7;
            int h   = g >> 1;
            int p   = w*8 + grp;
            long long gpt = g0 + p;
            int b  = (int)(gpt / NPTS);
            int pt = (int)(gpt - (long long)b*NPTS);
            float cx = coords_lds[p*3], cy = coords_lds[p*3+1], cz = coords_lds[p*3+2];

            float4 k4[8];
            {
                const float4* Krow = reinterpret_cast<const float4*>(&K_f[p*260 + g*32]);
                #pragma unroll
                for (int j = 0; j < 8; j++) k4[j] = Krow[j];
            }
            int cells_[3];
            #pragma unroll
            for (int pl = 0; pl < 3; pl++){
                float a = (pl == 2) ? cy : cx;
                float bb = (pl == 0) ? cy : cz;
                float ua = __fmul_rn(__fadd_rn(__fmul_rn(a, 0.5f), 0.5f), (float)(GG-1));
                float ub = __fmul_rn(__fadd_rn(__fmul_rn(bb,0.5f), 0.5f), (float)(GG-1));
                int gx = (int)ua; gx = gx < 0 ? 0 : (gx > GG-1 ? GG-1 : gx);
                int gy = (int)ub; gy = gy < 0 ? 0 : (gy > GG-1 ? GG-1 : gy);
                cells_[pl] = gx*GG + gy;
            }
            #pragma unroll
            for (int pl = 0; pl < 3; pl++){
                const float4* qrow = reinterpret_cast<const float4*>(
                    qT + ((size_t)pl*G2 + cells_[pl])*CC + g*32);
                float a0 = 0.f, a1 = 0.f, a2 = 0.f, a3 = 0.f;
                #pragma unroll
                for (int j = 0; j < 8; j++){
                    float4 q4 = qrow[j];
                    a0 = fmaf(k4[j].x, q4.x, a0);
                    a1 = fmaf(k4[j].y, q4.y, a1);
                    a2 = fmaf(k4[j].z, q4.z, a2);
                    a3 = fmaf(k4[j].w, q4.w, a3);
                }
                float sh = (a0 + a1) + (a2 + a3);
                sh += __shfl_xor(sh, 1);
                if ((lane & 1) == 0)
                    s_out[((size_t)(b*3 + pl)*NPTS + pt)*HH + h] = sh;
            }
        }
        __syncthreads();       // K_f reads done before next tile's A pack
    }
}

__global__ __launch_bounds__(256) void fill_kernel(
    const int* __restrict__ cells, int* __restrict__ startm,
    int* __restrict__ plist)
{
    int g = blockIdx.x * 256 + threadIdx.x;
    if (g >= NB*NPTS) return;
    int b = g / NPTS, pt = g % NPTS;
    #pragma unroll
    for (int pl = 0; pl < 3; pl++){
        int bp = b*3 + pl;
        int cell = cells[(size_t)bp*NPTS + pt];
        int pos = atomicAdd(&startm[(size_t)bp*G2 + cell], 1);
        plist[pos] = pt;
    }
}

__global__ __launch_bounds__(1024) void scan_kernel(
    const int* __restrict__ cnt, int* __restrict__ startm,
    int* __restrict__ worklist, int* __restrict__ nwork)
{
    __shared__ int sums[1024];
    __shared__ int sumc[1024];
    const int PER = (NB*3*G2) / 1024; // 96
    int t = threadIdx.x;
    int base = t * PER;
    int s = 0, sc = 0;
    for (int i = 0; i < PER; i++){
        int c = cnt[base + i];
        s += c;
        sc += (c + CHUNK-1) >> 8;
    }
    sums[t] = s; sumc[t] = sc;
    __syncthreads();
    for (int off = 1; off < 1024; off <<= 1){
        int v  = (t >= off) ? sums[t - off] : 0;
        int vc = (t >= off) ? sumc[t - off] : 0;
        __syncthreads();
        sums[t] += v; sumc[t] += vc;
        __syncthreads();
    }
    int excl  = (t == 0) ? 0 : sums[t - 1];
    int exclc = (t == 0) ? 0 : sumc[t - 1];
    for (int i = 0; i < PER; i++){
        int c = cnt[base + i];
        startm[base + i] = excl;
        excl += c;
        int nch = (c + CHUNK-1) >> 8;
        for (int ci = 0; ci < nch; ci++)
            worklist[exclc++] = ((base + i) << 8) | ci;
    }
    if (t == 1023) nwork[0] = exclc;
}

__global__ __launch_bounds__(256) void gather_kernel(
    const int* __restrict__ plist, const int* __restrict__ startm,
    const int* __restrict__ cnt, const float* __restrict__ s_in,
    const unsigned short* __restrict__ V, const int* __restrict__ worklist,
    const int* __restrict__ nwork, float* __restrict__ out,
    float* __restrict__ den_tmp)
{
    int lane = threadIdx.x & 63;
    int wi = blockIdx.x * 4 + (threadIdx.x >> 6);
    if (wi >= nwork[0]) return;
    int item = worklist[wi];
    int cellg = item >> 8;
    int ci = item & 255;
    int bp = cellg >> 14;
    int b = bp / 3;
    int h = lane >> 4;

    int end = startm[cellg];
    int n = cnt[cellg];
    int begin = end - n;

    const unsigned short* Vb = V + (size_t)b*NPTS*CC;
    const float* sb = s_in + (size_t)bp*NPTS*HH;

    float m0 = -INFINITY, m1 = -INFINITY, m2 = -INFINITY, m3 = -INFINITY;
    for (int chunk = begin; chunk < end; chunk += 64){
        int i = chunk + lane;
        if (i < end){
            int p = plist[i];
            float4 sv = *reinterpret_cast<const float4*>(sb + (size_t)p*HH);
            m0 = fmaxf(m0, sv.x); m1 = fmaxf(m1, sv.y);
            m2 = fmaxf(m2, sv.z); m3 = fmaxf(m3, sv.w);
        }
    }
    #pragma unroll
    for (int off = 32; off; off >>= 1){
        m0 = fmaxf(m0, __shfl_xor(m0, off));
        m1 = fmaxf(m1, __shfl_xor(m1, off));
        m2 = fmaxf(m2, __shfl_xor(m2, off));
        m3 = fmaxf(m3, __shfl_xor(m3, off));
    }
    float smh = (h == 0) ? m0 : (h == 1) ? m1 : (h == 2) ? m2 : m3;

    int cb = begin + ci*CHUNK;
    int ce = min(cb + CHUNK, end);
    float ax = 0.f, ay = 0.f, az = 0.f, aw = 0.f, den = 0.f;
    for (int chunk = cb; chunk < ce; chunk += 64){
        int m = min(64, ce - chunk);
        int pid = (lane < m) ? plist[chunk + lane] : 0;
        int j = 0;
        for (; j + 4 <= m; j += 4){
            int p0 = __shfl(pid, j  ), p1 = __shfl(pid, j+1);
            int p2 = __shfl(pid, j+2), p3 = __shfl(pid, j+3);
            float e0 = expf(sb[(size_t)p0*HH + h] - smh);
            float e1 = expf(sb[(size_t)p1*HH + h] - smh);
            float e2 = expf(sb[(size_t)p2*HH + h] - smh);
            float e3 = expf(sb[(size_t)p3*HH + h] - smh);
            ushort4 v0 = reinterpret_cast<const ushort4*>(Vb + (size_t)p0*CC)[lane];
            ushort4 v1 = reinterpret_cast<const ushort4*>(Vb + (size_t)p1*CC)[lane];
            ushort4 v2 = reinterpret_cast<const ushort4*>(Vb + (size_t)p2*CC)[lane];
            ushort4 v3 = reinterpret_cast<const ushort4*>(Vb + (size_t)p3*CC)[lane];
            ax = fmaf(e0, bfval(v0.x), ax); ay = fmaf(e0, bfval(v0.y), ay);
            az = fmaf(e0, bfval(v0.z), az); aw = fmaf(e0, bfval(v0.w), aw);
            ax = fmaf(e1, bfval(v1.x), ax); ay = fmaf(e1, bfval(v1.y), ay);
            az = fmaf(e1, bfval(v1.z), az); aw = fmaf(e1, bfval(v1.w), aw);
            ax = fmaf(e2, bfval(v2.x), ax); ay = fmaf(e2, bfval(v2.y), ay);
            az = fmaf(e2, bfval(v2.z), az); aw = fmaf(e2, bfval(v2.w), aw);
            ax = fmaf(e3, bfval(v3.x), ax); ay = fmaf(e3, bfval(v3.y), ay);
            az = fmaf(e3, bfval(v3.z), az); aw = fmaf(e3, bfval(v3.w), aw);
            den += (e0 + e1) + (e2 + e3);
        }
        for (; j < m; ++j){
            int p0 = __shfl(pid, j);
            float e0 = expf(sb[(size_t)p0*HH + h] - smh);
            ushort4 v0 = reinterpret_cast<const ushort4*>(Vb + (size_t)p0*CC)[lane];
            ax = fmaf(e0, bfval(v0.x), ax); ay = fmaf(e0, bfval(v0.y), ay);
            az = fmaf(e0, bfval(v0.z), az); aw = fmaf(e0, bfval(v0.w), aw);
            den += e0;
        }
    }

    if (n <= CHUNK){
        float d = fmaxf(den, 1e-30f);
        float4 o = make_float4(ax/d, ay/d, az/d, aw/d);
        reinterpret_cast<float4*>(out + (size_t)cellg*CC)[lane] = o;
    } else {
        float* op = out + (size_t)cellg*CC + lane*4;
        atomicAdd(&op[0], ax);
        atomicAdd(&op[1], ay);
        atomicAdd(&op[2], az);
        atomicAdd(&op[3], aw);
        if ((lane & 15) == 0)
            atomicAdd(&den_tmp[(size_t)cellg*HH + h], den);
    }
}

__global__ __launch_bounds__(256) void final_norm_kernel(
    const int* __restrict__ cnt, const float* __restrict__ den_tmp,
    float* __restrict__ out)
{
    int t = threadIdx.x;
    int lane = t & 63;
    int cellg = blockIdx.x * 4 + (t >> 6);
    if (cnt[cellg] <= CHUNK) return;
    float d = fmaxf(den_tmp[(size_t)cellg*HH + (lane >> 4)], 1e-30f);
    float4* o4 = reinterpret_cast<float4*>(out + (size_t)cellg*CC);
    float4 v = o4[lane];
    v.x /= d; v.y /= d; v.z /= d; v.w /= d;
    o4[lane] = v;
}

extern "C" void kernel_launch(void* const* d_in, const int* in_sizes, int n_in,
                              void* d_out, int out_size, void* d_ws, size_t ws_size,
                              hipStream_t stream)
{
    const float* feats  = (const float*)d_in[0];
    const float* bounds = (const float*)d_in[1];
    const float* qxy = (const float*)d_in[2];
    const float* qxz = (const float*)d_in[3];
    const float* qyz = (const float*)d_in[4];
    const float* Wk  = (const float*)d_in[5];
    const float* kb  = (const float*)d_in[6];
    const float* Wv  = (const float*)d_in[7];
    const float* vb  = (const float*)d_in[8];
    const float* lng = (const float*)d_in[9];
    const float* lnb = (const float*)d_in[10];

    char* ws = (char*)d_ws;
    float* qT            = (float*)(ws);                      //  50,331,648
    unsigned short* B2   = (unsigned short*)(ws + 50331648);  //     786,432
    float* bias_comb     = (float*)(ws + 51118080);           //       2,048
    unsigned short* Vbuf = (unsigned short*)(ws + 51120128);  // 102,400,000
    float* s_buf         = (float*)(ws + 153520128);          //   9,600,000
    int* cnt             = (int*)(ws + 163120128);            //     393,216
    int* startm          = (int*)(ws + 163513344);            //     393,216
    int* plist           = (int*)(ws + 163906560);            //   2,400,000
    int* worklist        = (int*)(ws + 166306560);            //     442,368
    float* den_tmp       = (float*)(ws + 166748928);          //   1,572,864
    int* nwork           = (int*)(ws + 168321792);            //         128
    int* cells           = (int*)(ws + 168321920);            //   2,400,000
    if (ws_size < 170721920ull) return;

    hipMemsetAsync(d_out, 0, (size_t)out_size * sizeof(float), stream);
    hipMemsetAsync(den_tmp, 0, (size_t)NB*3*G2*HH*sizeof(float), stream);
    hipMemsetAsync(cnt, 0, (size_t)NB*3*G2*sizeof(int), stream);
    prep_b2_kernel<<<512, 256, 0, stream>>>(Wk, Wv, kb, vb, B2, bias_comb);
    transpose_q_kernel<<<3072, 256, 0, stream>>>(qxy, qxz, qyz, qT);
    point64_kernel<<<PBLK, 512, 0, stream>>>(feats, bounds, B2, bias_comb,
                                             lng, lnb, qT, Vbuf, s_buf,
                                             cells, cnt);
    scan_kernel<<<1, 1024, 0, stream>>>(cnt, startm, worklist, nwork);
    fill_kernel<<<(NB*NPTS + 255)/256, 256, 0, stream>>>(cells, startm, plist);
    gather_kernel<<<27648, 256, 0, stream>>>(plist, startm, cnt, s_buf,
                                             Vbuf, worklist, nwork,
                                             (float*)d_out, den_tmp);
    final_norm_kernel<<<24576, 256, 0, stream>>>(cnt, den_tmp, (float*)d_out);
}

// Round 20
// 974.276 us; speedup vs baseline: 1.1061x; 1.1061x over previous
//
#include <hip/hip_runtime.h>
#include <hip/hip_bf16.h>

#define GG 128
#define G2 (GG*GG)
#define CC 256
#define HH 4
#define NPTS 100000
#define NB 2
#define LN_EPS 1e-5f
#define CHUNK 256

typedef __attribute__((ext_vector_type(8))) short short8v;
typedef __attribute__((ext_vector_type(4))) float float4v;

__device__ __forceinline__ unsigned short bfround(float x){
    unsigned u = __float_as_uint(x);
    return (unsigned short)((u + 0x7FFFu + ((u >> 16) & 1u)) >> 16);
}
__device__ __forceinline__ float bfval(unsigned short h){
    return __uint_as_float(((unsigned)h) << 16);
}

__global__ __launch_bounds__(256) void prep_b2_kernel(
    const float* __restrict__ Wk, const float* __restrict__ Wv,
    const float* __restrict__ kb, const float* __restrict__ vb,
    unsigned short* __restrict__ B2, float* __restrict__ bias_comb)
{
    int n = blockIdx.x;
    int t = threadIdx.x;
    const float* src = (n < 256) ? (Wk + (size_t)n*CC) : (Wv + (size_t)(n-256)*CC);
    float w = src[t];
    unsigned short h = bfround(w);
    unsigned short l = bfround(w - bfval(h));
    unsigned short* row = B2 + (size_t)n*768;
    row[t] = h;
    row[256 + t] = l;
    row[512 + t] = h;
    if (t == 0) bias_comb[n] = (n < 256) ? kb[n] : vb[n-256];
}

__global__ __launch_bounds__(256) void transpose_q_kernel(
    const float* __restrict__ qxy, const float* __restrict__ qxz,
    const float* __restrict__ qyz, float* __restrict__ qT)
{
    int blk = blockIdx.x;
    int plane = blk >> 10;
    int rem = blk & 1023;
    int cell0 = (rem >> 2) << 6;
    int c0 = (rem & 3) << 6;
    const float* q = plane == 0 ? qxy : (plane == 1 ? qxz : qyz);
    __shared__ float tile[64][65];
    int tx = threadIdx.x & 63;
    int ty = threadIdx.x >> 6;
    #pragma unroll
    for (int i = ty; i < 64; i += 4)
        tile[i][tx] = q[(size_t)(c0 + i)*G2 + cell0 + tx];
    __syncthreads();
    #pragma unroll
    for (int i = ty; i < 64; i += 4)
        qT[((size_t)plane*G2 + cell0 + i)*CC + c0 + tx] = tile[tx][i];
}

// ===== R17-exact fused M=64 kernel (best measured: 496 us) =====
__global__ __launch_bounds__(512, 4) void point64_kernel(
    const float* __restrict__ feats, const float* __restrict__ bounds,
    const unsigned short* __restrict__ B2, const float* __restrict__ bias_comb,
    const float* __restrict__ lng, const float* __restrict__ lnb,
    const float* __restrict__ qT,
    unsigned short* __restrict__ Vout, float* __restrict__ s_out,
    int* __restrict__ cells, int* __restrict__ cnt)
{
    __shared__ __align__(16) char lraw[68352];
    unsigned short* Ahi = (unsigned short*)lraw;
    unsigned short* Alo = (unsigned short*)(lraw + 33792);
    float* K_f = (float*)lraw;
    float* coords_lds = (float*)(lraw + 67584);

    int t = threadIdx.x;
    int lane = t & 63;
    int w = t >> 6;                    // 0..7
    long long g0 = (long long)blockIdx.x * 64;   // 64*3125 = 200000 exactly

    float xr[8][4];
    #pragma unroll
    for (int r = 0; r < 8; r++){
        long long gpt = g0 + w*8 + r;
        const float* f = feats + (size_t)gpt*CC;
        xr[r][0] = f[lane];
        xr[r][1] = f[lane + 64];
        xr[r][2] = f[lane + 128];
        xr[r][3] = f[lane + 192];
    }

    float lg0 = lng[lane], lg1 = lng[lane+64], lg2 = lng[lane+128], lg3 = lng[lane+192];
    float lb0 = lnb[lane], lb1 = lnb[lane+64], lb2 = lnb[lane+128], lb3 = lnb[lane+192];
    #pragma unroll
    for (int r = 0; r < 8; r++){
        int p = w*8 + r;
        float x0 = xr[r][0], x1 = xr[r][1], x2 = xr[r][2], x3 = xr[r][3];
        if (lane < 3){
            float l0 = bounds[2*lane], h0 = bounds[2*lane+1];
            float tnum = __fmul_rn(2.0f, __fsub_rn(x0, l0));
            float cv = __fsub_rn(__fdiv_rn(tnum, __fsub_rn(h0, l0)), 1.0f);
            x0 = cv;
            coords_lds[p*3 + lane] = cv;
        }
        float s1 = x0 + x1 + x2 + x3;
        float s2 = x0*x0 + x1*x1 + x2*x2 + x3*x3;
        #pragma unroll
        for (int off = 32; off; off >>= 1){
            s1 += __shfl_xor(s1, off);
            s2 += __shfl_xor(s2, off);
        }
        float mu = s1 * (1.0f/CC);
        float var = s2 * (1.0f/CC) - mu*mu;
        float rs = rsqrtf(var + LN_EPS);

        float f0 = (x0 - mu)*rs*lg0 + lb0;
        float f1 = (x1 - mu)*rs*lg1 + lb1;
        float f2 = (x2 - mu)*rs*lg2 + lb2;
        float f3 = (x3 - mu)*rs*lg3 + lb3;
        unsigned short h0 = bfround(f0), h1 = bfround(f1);
        unsigned short h2 = bfround(f2), h3 = bfround(f3);
        Ahi[p*264 + lane      ] = h0;  Alo[p*264 + lane      ] = bfround(f0 - bfval(h0));
        Ahi[p*264 + lane +  64] = h1;  Alo[p*264 + lane +  64] = bfround(f1 - bfval(h1));
        Ahi[p*264 + lane + 128] = h2;  Alo[p*264 + lane + 128] = bfround(f2 - bfval(h2));
        Ahi[p*264 + lane + 192] = h3;  Alo[p*264 + lane + 192] = bfround(f3 - bfval(h3));
    }
    __syncthreads();

    if (lane < 24){
        int r = lane / 3;
        int pl = lane - 3*r;
        int p = w*8 + r;
        long long gpt = g0 + p;
        int bb = (int)(gpt / NPTS);
        int ptp = (int)(gpt - (long long)bb*NPTS);
        float cx = coords_lds[p*3], cy = coords_lds[p*3+1], cz = coords_lds[p*3+2];
        float a = (pl == 2) ? cy : cx;
        float b2 = (pl == 0) ? cy : cz;
        float ua = __fmul_rn(__fadd_rn(__fmul_rn(a, 0.5f), 0.5f), (float)(GG-1));
        float ub = __fmul_rn(__fadd_rn(__fmul_rn(b2,0.5f), 0.5f), (float)(GG-1));
        int gx = (int)ua; gx = gx < 0 ? 0 : (gx > GG-1 ? GG-1 : gx);
        int gy = (int)ub; gy = gy < 0 ? 0 : (gy > GG-1 ? GG-1 : gy);
        int cell = gx*GG + gy;
        int bp = bb*3 + pl;
        cells[(size_t)bp*NPTS + ptp] = cell;
        atomicAdd(&cnt[(size_t)bp*G2 + cell], 1);
    }

    {
        int apt = lane & 15;
        int krow = (lane >> 4) * 8;
        int n0 = w * 64;
        int bcol = n0 + (lane & 15);
        float4v acc[4][4];
        #pragma unroll
        for (int ni = 0; ni < 4; ni++){
            float bz = bias_comb[n0 + ni*16 + (lane & 15)];
            #pragma unroll
            for (int mi = 0; mi < 4; mi++){
                acc[mi][ni][0]=bz; acc[mi][ni][1]=bz;
                acc[mi][ni][2]=bz; acc[mi][ni][3]=bz;
            }
        }
        #pragma unroll 2
        for (int ks = 0; ks < 24; ks++){
            int term = ks >> 3;
            int kk = (ks & 7)*32 + krow;
            int kglob = term*256 + kk;
            const unsigned short* Abase = (term < 2) ? Ahi : Alo;
            short8v a[4];
            #pragma unroll
            for (int mi = 0; mi < 4; mi++)
                a[mi] = *reinterpret_cast<const short8v*>(Abase + (mi*16 + apt)*264 + kk);
            short8v bf[4];
            #pragma unroll
            for (int ni = 0; ni < 4; ni++)
                bf[ni] = *reinterpret_cast<const short8v*>(
                    B2 + (size_t)(bcol + ni*16)*768 + kglob);
            #pragma unroll
            for (int mi = 0; mi < 4; mi++)
                #pragma unroll
                for (int ni = 0; ni < 4; ni++)
                    acc[mi][ni] = __builtin_amdgcn_mfma_f32_16x16x32_bf16(
                        a[mi], bf[ni], acc[mi][ni], 0, 0, 0);
        }
        __syncthreads();
        if (w < 4){
            #pragma unroll
            for (int ni = 0; ni < 4; ni++){
                int ch = n0 + ni*16 + (lane & 15);
                #pragma unroll
                for (int mi = 0; mi < 4; mi++)
                    #pragma unroll
                    for (int r4 = 0; r4 < 4; r4++){
                        int pt = mi*16 + (lane >> 4)*4 + r4;
                        K_f[pt*260 + ch] = acc[mi][ni][r4];
                    }
            }
        } else {
            #pragma unroll
            for (int ni = 0; ni < 4; ni++){
                int ch = (n0 - 256) + ni*16 + (lane & 15);
                #pragma unroll
                for (int mi = 0; mi < 4; mi++)
                    #pragma unroll
                    for (int r4 = 0; r4 < 4; r4++){
                        int pt = mi*16 + (lane >> 4)*4 + r4;
                        Vout[(size_t)(g0 + pt)*CC + ch] = bfround(acc[mi][ni][r4]);
                    }
            }
        }
    }
    __syncthreads();

    {
        int grp = lane >> 3;
        int g   = lane & 7;
        int h   = g >> 1;
        int p   = w*8 + grp;
        long long gpt = g0 + p;
        int b  = (int)(gpt / NPTS);
        int pt = (int)(gpt - (long long)b*NPTS);
        float cx = coords_lds[p*3], cy = coords_lds[p*3+1], cz = coords_lds[p*3+2];

        float4 k4[8];
        {
            const float4* Krow = reinterpret_cast<const float4*>(&K_f[p*260 + g*32]);
            #pragma unroll
            for (int j = 0; j < 8; j++) k4[j] = Krow[j];
        }
        int cells_[3];
        #pragma unroll
        for (int pl = 0; pl < 3; pl++){
            float a = (pl == 2) ? cy : cx;
            float bb = (pl == 0) ? cy : cz;
            float ua = __fmul_rn(__fadd_rn(__fmul_rn(a, 0.5f), 0.5f), (float)(GG-1));
            float ub = __fmul_rn(__fadd_rn(__fmul_rn(bb,0.5f), 0.5f), (float)(GG-1));
            int gx = (int)ua; gx = gx < 0 ? 0 : (gx > GG-1 ? GG-1 : gx);
            int gy = (int)ub; gy = gy < 0 ? 0 : (gy > GG-1 ? GG-1 : gy);
            cells_[pl] = gx*GG + gy;
        }
        #pragma unroll
        for (int pl = 0; pl < 3; pl++){
            const float4* qrow = reinterpret_cast<const float4*>(
                qT + ((size_t)pl*G2 + cells_[pl])*CC + g*32);
            float a0 = 0.f, a1 = 0.f, a2 = 0.f, a3 = 0.f;
            #pragma unroll
            for (int j = 0; j < 8; j++){
                float4 q4 = qrow[j];
                a0 = fmaf(k4[j].x, q4.x, a0);
                a1 = fmaf(k4[j].y, q4.y, a1);
                a2 = fmaf(k4[j].z, q4.z, a2);
                a3 = fmaf(k4[j].w, q4.w, a3);
            }
            float sh = (a0 + a1) + (a2 + a3);
            sh += __shfl_xor(sh, 1);
            if ((lane & 1) == 0)
                s_out[((size_t)(b*3 + pl)*NPTS + pt)*HH + h] = sh;
        }
    }
}

__global__ __launch_bounds__(256) void fill_kernel(
    const int* __restrict__ cells, int* __restrict__ startm,
    int* __restrict__ plist)
{
    int g = blockIdx.x * 256 + threadIdx.x;
    if (g >= NB*NPTS) return;
    int b = g / NPTS, pt = g % NPTS;
    #pragma unroll
    for (int pl = 0; pl < 3; pl++){
        int bp = b*3 + pl;
        int cell = cells[(size_t)bp*NPTS + pt];
        int pos = atomicAdd(&startm[(size_t)bp*G2 + cell], 1);
        plist[pos] = pt;
    }
}

__global__ __launch_bounds__(1024) void scan_kernel(
    const int* __restrict__ cnt, int* __restrict__ startm,
    int* __restrict__ worklist, int* __restrict__ nwork)
{
    __shared__ int sums[1024];
    __shared__ int sumc[1024];
    const int PER = (NB*3*G2) / 1024; // 96
    int t = threadIdx.x;
    int base = t * PER;
    int s = 0, sc = 0;
    for (int i = 0; i < PER; i++){
        int c = cnt[base + i];
        s += c;
        sc += (c + CHUNK-1) >> 8;
    }
    sums[t] = s; sumc[t] = sc;
    __syncthreads();
    for (int off = 1; off < 1024; off <<= 1){
        int v  = (t >= off) ? sums[t - off] : 0;
        int vc = (t >= off) ? sumc[t - off] : 0;
        __syncthreads();
        sums[t] += v; sumc[t] += vc;
        __syncthreads();
    }
    int excl  = (t == 0) ? 0 : sums[t - 1];
    int exclc = (t == 0) ? 0 : sumc[t - 1];
    for (int i = 0; i < PER; i++){
        int c = cnt[base + i];
        startm[base + i] = excl;
        excl += c;
        int nch = (c + CHUNK-1) >> 8;
        for (int ci = 0; ci < nch; ci++)
            worklist[exclc++] = ((base + i) << 8) | ci;
    }
    if (t == 1023) nwork[0] = exclc;
}

// R20 gather: s+exp hoisted to per-lane preload; inner loop has NO s loads.
__global__ __launch_bounds__(256) void gather_kernel(
    const int* __restrict__ plist, const int* __restrict__ startm,
    const int* __restrict__ cnt, const float* __restrict__ s_in,
    const unsigned short* __restrict__ V, const int* __restrict__ worklist,
    const int* __restrict__ nwork, float* __restrict__ out,
    float* __restrict__ den_tmp)
{
    int lane = threadIdx.x & 63;
    int wi = blockIdx.x * 4 + (threadIdx.x >> 6);
    if (wi >= nwork[0]) return;
    int item = worklist[wi];
    int cellg = item >> 8;
    int ci = item & 255;
    int bp = cellg >> 14;
    int b = bp / 3;
    int h = lane >> 4;

    int end = startm[cellg];
    int n = cnt[cellg];
    int begin = end - n;

    const unsigned short* Vb = V + (size_t)b*NPTS*CC;
    const float* sb = s_in + (size_t)bp*NPTS*HH;

    // ---- prepass: per-head max over the FULL cell ----
    float m0 = -INFINITY, m1 = -INFINITY, m2 = -INFINITY, m3 = -INFINITY;
    for (int chunk = begin; chunk < end; chunk += 64){
        int i = chunk + lane;
        if (i < end){
            int p = plist[i];
            float4 sv = *reinterpret_cast<const float4*>(sb + (size_t)p*HH);
            m0 = fmaxf(m0, sv.x); m1 = fmaxf(m1, sv.y);
            m2 = fmaxf(m2, sv.z); m3 = fmaxf(m3, sv.w);
        }
    }
    #pragma unroll
    for (int off = 32; off; off >>= 1){
        m0 = fmaxf(m0, __shfl_xor(m0, off));
        m1 = fmaxf(m1, __shfl_xor(m1, off));
        m2 = fmaxf(m2, __shfl_xor(m2, off));
        m3 = fmaxf(m3, __shfl_xor(m3, off));
    }

    // ---- main pass over this chunk: e precomputed per-lane, shfl-broadcast ----
    int cb = begin + ci*CHUNK;
    int ce = min(cb + CHUNK, end);
    float ax = 0.f, ay = 0.f, az = 0.f, aw = 0.f, den = 0.f;
    for (int chunk = cb; chunk < ce; chunk += 64){
        int m = min(64, ce - chunk);
        int pid = 0;
        float e0o = 0.f, e1o = 0.f, e2o = 0.f, e3o = 0.f;
        if (lane < m){
            pid = plist[chunk + lane];
            float4 sv = *reinterpret_cast<const float4*>(sb + (size_t)pid*HH);
            e0o = expf(sv.x - m0);
            e1o = expf(sv.y - m1);
            e2o = expf(sv.z - m2);
            e3o = expf(sv.w - m3);
        }
        int j = 0;
        for (; j + 4 <= m; j += 4){
            int p0 = __shfl(pid, j  ), p1 = __shfl(pid, j+1);
            int p2 = __shfl(pid, j+2), p3 = __shfl(pid, j+3);
            float q00 = __shfl(e0o, j  ), q01 = __shfl(e1o, j  ),
                  q02 = __shfl(e2o, j  ), q03 = __shfl(e3o, j  );
            float q10 = __shfl(e0o, j+1), q11 = __shfl(e1o, j+1),
                  q12 = __shfl(e2o, j+1), q13 = __shfl(e3o, j+1);
            float q20 = __shfl(e0o, j+2), q21 = __shfl(e1o, j+2),
                  q22 = __shfl(e2o, j+2), q23 = __shfl(e3o, j+2);
            float q30 = __shfl(e0o, j+3), q31 = __shfl(e1o, j+3),
                  q32 = __shfl(e2o, j+3), q33 = __shfl(e3o, j+3);
            float e0 = (h == 0) ? q00 : (h == 1) ? q01 : (h == 2) ? q02 : q03;
            float e1 = (h == 0) ? q10 : (h == 1) ? q11 : (h == 2) ? q12 : q13;
            float e2 = (h == 0) ? q20 : (h == 1) ? q21 : (h == 2) ? q22 : q23;
            float e3 = (h == 0) ? q30 : (h == 1) ? q31 : (h == 2) ? q32 : q33;
            ushort4 v0 = reinterpret_cast<const ushort4*>(Vb + (size_t)p0*CC)[lane];
            ushort4 v1 = reinterpret_cast<const ushort4*>(Vb + (size_t)p1*CC)[lane];
            ushort4 v2 = reinterpret_cast<const ushort4*>(Vb + (size_t)p2*CC)[lane];
            ushort4 v3 = reinterpret_cast<const ushort4*>(Vb + (size_t)p3*CC)[lane];
            ax = fmaf(e0, bfval(v0.x), ax); ay = fmaf(e0, bfval(v0.y), ay);
            az = fmaf(e0, bfval(v0.z), az); aw = fmaf(e0, bfval(v0.w), aw);
            ax = fmaf(e1, bfval(v1.x), ax); ay = fmaf(e1, bfval(v1.y), ay);
            az = fmaf(e1, bfval(v1.z), az); aw = fmaf(e1, bfval(v1.w), aw);
            ax = fmaf(e2, bfval(v2.x), ax); ay = fmaf(e2, bfval(v2.y), ay);
            az = fmaf(e2, bfval(v2.z), az); aw = fmaf(e2, bfval(v2.w), aw);
            ax = fmaf(e3, bfval(v3.x), ax); ay = fmaf(e3, bfval(v3.y), ay);
            az = fmaf(e3, bfval(v3.z), az); aw = fmaf(e3, bfval(v3.w), aw);
            den += (e0 + e1) + (e2 + e3);
        }
        for (; j < m; ++j){
            int p0 = __shfl(pid, j);
            float q0 = __shfl(e0o, j), q1 = __shfl(e1o, j),
                  q2 = __shfl(e2o, j), q3 = __shfl(e3o, j);
            float e0 = (h == 0) ? q0 : (h == 1) ? q1 : (h == 2) ? q2 : q3;
            ushort4 v0 = reinterpret_cast<const ushort4*>(Vb + (size_t)p0*CC)[lane];
            ax = fmaf(e0, bfval(v0.x), ax); ay = fmaf(e0, bfval(v0.y), ay);
            az = fmaf(e0, bfval(v0.z), az); aw = fmaf(e0, bfval(v0.w), aw);
            den += e0;
        }
    }

    if (n <= CHUNK){
        float d = fmaxf(den, 1e-30f);
        float4 o = make_float4(ax/d, ay/d, az/d, aw/d);
        reinterpret_cast<float4*>(out + (size_t)cellg*CC)[lane] = o;
    } else {
        float* op = out + (size_t)cellg*CC + lane*4;
        atomicAdd(&op[0], ax);
        atomicAdd(&op[1], ay);
        atomicAdd(&op[2], az);
        atomicAdd(&op[3], aw);
        if ((lane & 15) == 0)
            atomicAdd(&den_tmp[(size_t)cellg*HH + h], den);
    }
}

__global__ __launch_bounds__(256) void final_norm_kernel(
    const int* __restrict__ cnt, const float* __restrict__ den_tmp,
    float* __restrict__ out)
{
    int t = threadIdx.x;
    int lane = t & 63;
    int cellg = blockIdx.x * 4 + (t >> 6);
    if (cnt[cellg] <= CHUNK) return;
    float d = fmaxf(den_tmp[(size_t)cellg*HH + (lane >> 4)], 1e-30f);
    float4* o4 = reinterpret_cast<float4*>(out + (size_t)cellg*CC);
    float4 v = o4[lane];
    v.x /= d; v.y /= d; v.z /= d; v.w /= d;
    o4[lane] = v;
}

extern "C" void kernel_launch(void* const* d_in, const int* in_sizes, int n_in,
                              void* d_out, int out_size, void* d_ws, size_t ws_size,
                              hipStream_t stream)
{
    const float* feats  = (const float*)d_in[0];
    const float* bounds = (const float*)d_in[1];
    const float* qxy = (const float*)d_in[2];
    const float* qxz = (const float*)d_in[3];
    const float* qyz = (const float*)d_in[4];
    const float* Wk  = (const float*)d_in[5];
    const float* kb  = (const float*)d_in[6];
    const float* Wv  = (const float*)d_in[7];
    const float* vb  = (const float*)d_in[8];
    const float* lng = (const float*)d_in[9];
    const float* lnb = (const float*)d_in[10];

    char* ws = (char*)d_ws;
    float* qT            = (float*)(ws);                      //  50,331,648
    unsigned short* B2   = (unsigned short*)(ws + 50331648);  //     786,432
    float* bias_comb     = (float*)(ws + 51118080);           //       2,048
    unsigned short* Vbuf = (unsigned short*)(ws + 51120128);  // 102,400,000
    float* s_buf         = (float*)(ws + 153520128);          //   9,600,000
    int* cnt             = (int*)(ws + 163120128);            //     393,216
    int* startm          = (int*)(ws + 163513344);            //     393,216
    int* plist           = (int*)(ws + 163906560);            //   2,400,000
    int* worklist        = (int*)(ws + 166306560);            //     442,368
    float* den_tmp       = (float*)(ws + 166748928);          //   1,572,864
    int* nwork           = (int*)(ws + 168321792);            //         128
    int* cells           = (int*)(ws + 168321920);            //   2,400,000
    if (ws_size < 170721920ull) return;

    hipMemsetAsync(d_out, 0, (size_t)out_size * sizeof(float), stream);
    hipMemsetAsync(den_tmp, 0, (size_t)NB*3*G2*HH*sizeof(float), stream);
    hipMemsetAsync(cnt, 0, (size_t)NB*3*G2*sizeof(int), stream);
    prep_b2_kernel<<<512, 256, 0, stream>>>(Wk, Wv, kb, vb, B2, bias_comb);
    transpose_q_kernel<<<3072, 256, 0, stream>>>(qxy, qxz, qyz, qT);
    point64_kernel<<<3125, 512, 0, stream>>>(feats, bounds, B2, bias_comb,
                                             lng, lnb, qT, Vbuf, s_buf,
                                             cells, cnt);
    scan_kernel<<<1, 1024, 0, stream>>>(cnt, startm, worklist, nwork);
    fill_kernel<<<(NB*NPTS + 255)/256, 256, 0, stream>>>(cells, startm, plist);
    gather_kernel<<<27648, 256, 0, stream>>>(plist, startm, cnt, s_buf,
                                             Vbuf, worklist, nwork,
                                             (float*)d_out, den_tmp);
    final_norm_kernel<<<24576, 256, 0, stream>>>(cnt, den_tmp, (float*)d_out);
}